// Round 8
// baseline (129.122 us; speedup 1.0000x reference)
//
#include <hip/hip_runtime.h>
#include <cstdint>

#define NB1 8192
#define NB2 8192
#define DDIM 128
#define KROW 256           // stored row: [hi(128) | lo(128)] f16

using half8   = __attribute__((ext_vector_type(8))) _Float16;
using half4   = __attribute__((ext_vector_type(4))) _Float16;
using float4v = __attribute__((ext_vector_type(4))) float;

typedef __attribute__((address_space(3))) void       lds_void;
typedef const __attribute__((address_space(1))) void glb_void;

__device__ inline unsigned long long packkey(float v, int j) {
  unsigned u = __float_as_uint(v);
  u = (u & 0x80000000u) ? ~u : (u | 0x80000000u);  // monotone float->uint
  return ((unsigned long long)u << 32) | (unsigned)j;
}

// ---------------------------------------------------------------------------
// Kernel 0: fp32 -> f16 hi/lo split (row = [hi|lo], 256 f16) + squared norms
// + init packed argmin keys. One wave per 2 rows; float4 loads, half4 stores.
// ---------------------------------------------------------------------------
__global__ __launch_bounds__(256) void convert_kernel(
    const float* __restrict__ d1, const float* __restrict__ d2,
    _Float16* __restrict__ A2, _Float16* __restrict__ B2,
    float* __restrict__ asq, float* __restrict__ bsq,
    unsigned long long* __restrict__ packed) {
  int gid  = blockIdx.x * 256 + threadIdx.x;
  int wv   = gid >> 6;
  int lane = gid & 63;
  int rowc = 2 * wv + (lane >> 5);
  bool isA = rowc < NB1;
  const float* src = isA ? d1 : d2;
  int row = isA ? rowc : rowc - NB1;
  int k4  = (lane & 31) * 4;

  float4 v = *(const float4*)&src[row * DDIM + k4];
  _Float16 h0 = (_Float16)v.x, h1 = (_Float16)v.y;
  _Float16 h2 = (_Float16)v.z, h3 = (_Float16)v.w;
  half4 hh = {h0, h1, h2, h3};
  half4 ll = {(_Float16)(v.x - (float)h0), (_Float16)(v.y - (float)h1),
              (_Float16)(v.z - (float)h2), (_Float16)(v.w - (float)h3)};

  _Float16* dst = (isA ? A2 : B2) + (size_t)row * KROW;
  *(half4*)&dst[k4]       = hh;
  *(half4*)&dst[128 + k4] = ll;

  float s = v.x * v.x + v.y * v.y + v.z * v.z + v.w * v.w;
  #pragma unroll
  for (int off = 16; off > 0; off >>= 1) s += __shfl_xor(s, off, 64);
  if ((lane & 31) == 0) (isA ? asq : bsq)[row] = s;

  if (gid < NB1) packed[gid] = 0xFFFFFFFFFFFFFFFFull;  // +inf key
}

// ---------------------------------------------------------------------------
// Kernel 1: MFMA GEMM (virtual K=384 f16, fp32 acc) + fused row argmin.
// Round-8: faithful m201 8-phase port. 256x256 tile, 512 thr, 8 waves
// (2M x 4N, per-wave 128x64 out, acc[8][4] in AGPR). BK=64 (2 virtual
// 32-f16 chunks), 6 K-tiles, 4 phases each:
//   PH(mh,ks): ds_read af[4] (+bf[4] if mh==0); issue 2 stage gloads for
//   K-tile kt+1; barrier; setprio1; 16 MFMA (acc[mh*4+r][c]); setprio0;
//   [vmcnt(4) after phases 1,3 only]; barrier.
// frag regs = af4+bf4 = 32 VGPR (bf held across the mh pair) -> fits the
// 128-VGPR half of the unified file (acc fills the 128-AGPR half). This is
// the phase-granular read-ahead the R5-R7 step-granular attempts couldn't
// afford.
// LDS: 2 buf x (A[2 ks][256 r][32 f16] + B same) = 128 KiB. ks-major layout
// keeps global_load_lds dests wave-linear; slot rotation (q+(R>>1))&3 within
// each 4x16B row is R1's verified conflict-free scheme (2 lanes/bank).
// Staging: 8 call-units per K-tile in consumption order
//   [A(0,0) B(0,0) B(1,0) A(1,0) A(0,1) B(0,1) B(1,1) A(1,1)], 2 per phase.
// vmcnt ledger (derived): drain c1..c4 at p3-trailing of previous tile,
// c5..c8 at p1-trailing -> vmcnt(4) steady, tail 0 at tile5-p1. Never 0
// mid-loop. WAR: stage(kt+1) targets buf (kt+1)&1 whose readers (tile kt-1)
// all finished before tile kt began.
// ---------------------------------------------------------------------------
__global__ __launch_bounds__(512, 2) void mfma_match_kernel(
    const _Float16* __restrict__ A2, const _Float16* __restrict__ B2,
    const float* __restrict__ bsq, unsigned long long* __restrict__ packed) {
  __shared__ unsigned long long smem[16384];  // 128 KiB
  _Float16* S  = (_Float16*)smem;
  char*     Sb = (char*)smem;

  const int t    = threadIdx.x;
  const int lane = t & 63;
  const int wid  = t >> 6;           // 0..7
  const int wm   = wid >> 2;         // 0..1 : 128-row band of A
  const int wn   = wid & 3;          // 0..3 : 64-col band of B
  const int lx   = lane & 15, q = lane >> 4;
  const int sw   = ((q + (lx >> 1)) & 3) * 8;  // conflict-free slot rotation

  // XCD swizzle: 1024 blocks over 8 XCDs; per-XCD 16x8 rectangle of tiles.
  const int id  = blockIdx.x;
  const int xcd = id & 7, kk = id >> 3;
  const int bx = (xcd & 1) * 16 + (kk & 15);
  const int by = (xcd >> 1) * 8 + (kk >> 4);
  const int row0 = bx * 256, col0 = by * 256;

  // Staging geometry: call = 512 cells of 16B, thread t -> row rp=t>>2,
  // slot s3=t&3 (linear LDS dest). Source chunk-cell = (s3-(row>>1))&3
  // (inverse of the read rotation); thread-constant across all calls.
  const int rp   = t >> 2;
  const int s3   = t & 3;
  const int qt   = (s3 - ((t >> 3) & 3)) & 3;
  const int aRow = (rp & 63) + ((rp >> 6) << 7);  // A-call rows: 0-63|128-191 (+mh*64)

  const _Float16* pA = A2 + (size_t)(row0 + aRow) * KROW + qt * 8;
  const _Float16* pB = B2 + (size_t)(col0 + rp) * KROW + qt * 8;
  const int dA = aRow * 64 + s3 * 16;   // LDS byte offset within A region
  const int dB = rp * 64 + s3 * 16;

  float4v acc[8][4];
  #pragma unroll
  for (int m = 0; m < 8; ++m)
    #pragma unroll
    for (int c = 0; c < 4; ++c) acc[m][c] = (float4v){0.f, 0.f, 0.f, 0.f};

  // Stage one call-unit. aK/bK = source 32-f16 chunk index (compile-time).
  auto stA = [&](int buf, int mh, int ks, int aK) {
    __builtin_amdgcn_global_load_lds(
        (glb_void*)(pA + mh * 16384 + aK * 32),
        (lds_void*)(Sb + buf * 65536 + ks * 16384 + mh * 4096 + dA), 16, 0, 0);
  };
  auto stB = [&](int buf, int rh, int ks, int bK) {
    __builtin_amdgcn_global_load_lds(
        (glb_void*)(pB + rh * 32768 + bK * 32),
        (lds_void*)(Sb + buf * 65536 + 32768 + ks * 16384 + rh * 8192 + dB),
        16, 0, 0);
  };

  half8 af[4], bf[4];
  auto rdA = [&](int buf, int mh, int ks) {
    const _Float16* Ab =
        S + buf * 32768 + ks * 8192 + (wm * 128 + mh * 64 + lx) * 32 + sw;
    #pragma unroll
    for (int r = 0; r < 4; ++r) af[r] = *(const half8*)&Ab[r * 512];
  };
  auto rdB = [&](int buf, int ks) {
    const _Float16* Bb =
        S + buf * 32768 + 16384 + ks * 8192 + (wn * 64 + lx) * 32 + sw;
    #pragma unroll
    for (int c = 0; c < 4; ++c) bf[c] = *(const half8*)&Bb[c * 512];
  };
  auto mfma16 = [&](int mh) {
    __builtin_amdgcn_s_setprio(1);
    #pragma unroll
    for (int r = 0; r < 4; ++r)
      #pragma unroll
      for (int c = 0; c < 4; ++c)
        acc[mh * 4 + r][c] = __builtin_amdgcn_mfma_f32_16x16x32_f16(
            af[r], bf[c], acc[mh * 4 + r][c], 0, 0, 0);
    __builtin_amdgcn_s_setprio(0);
  };

#define BAR() do { __builtin_amdgcn_s_barrier(); \
                   asm volatile("" ::: "memory"); } while (0)

  // Prologue: stage tile 0 (chunks a:0,1 b:0,1) in ledger order c1..c8.
  stA(0, 0, 0, 0); stB(0, 0, 0, 0); stB(0, 1, 0, 0); stA(0, 1, 0, 0);
  stA(0, 0, 1, 1); stB(0, 0, 1, 1); stB(0, 1, 1, 1); stA(0, 1, 1, 1);
  asm volatile("s_waitcnt vmcnt(4)" ::: "memory");  // c1..c4 landed
  BAR();

#define PH0(BUF, NBUF, AK0, BK0, DOST)                                \
  do { rdA(BUF, 0, 0); rdB(BUF, 0);                                   \
       if constexpr (DOST) { stA(NBUF, 0, 0, AK0); stB(NBUF, 0, 0, BK0); } \
       BAR(); mfma16(0); BAR(); } while (0)
#define PH1(BUF, NBUF, AK0, BK0, DOST, VM)                            \
  do { rdA(BUF, 1, 0);                                                \
       if constexpr (DOST) { stB(NBUF, 1, 0, BK0); stA(NBUF, 1, 0, AK0); } \
       BAR(); mfma16(1);                                              \
       asm volatile("s_waitcnt vmcnt(" VM ")" ::: "memory");          \
       BAR(); } while (0)
#define PH2(BUF, NBUF, AK1, BK1, DOST)                                \
  do { rdA(BUF, 0, 1); rdB(BUF, 1);                                   \
       if constexpr (DOST) { stA(NBUF, 0, 1, AK1); stB(NBUF, 0, 1, BK1); } \
       BAR(); mfma16(0); BAR(); } while (0)
#define PH3(BUF, NBUF, AK1, BK1, DOST, DOVM)                          \
  do { rdA(BUF, 1, 1);                                                \
       if constexpr (DOST) { stB(NBUF, 1, 1, BK1); stA(NBUF, 1, 1, AK1); } \
       BAR(); mfma16(1);                                              \
       if constexpr (DOVM)                                            \
         asm volatile("s_waitcnt vmcnt(4)" ::: "memory");             \
       BAR(); } while (0)

#define TILE(BUF, NBUF, AK0, AK1, BK0, BK1, DOST, VM1, DOVM3)         \
  PH0(BUF, NBUF, AK0, BK0, DOST);                                     \
  PH1(BUF, NBUF, AK0, BK0, DOST, VM1);                                \
  PH2(BUF, NBUF, AK1, BK1, DOST);                                     \
  PH3(BUF, NBUF, AK1, BK1, DOST, DOVM3)

  // Virtual chunks per K-tile j: v=2j,2j+1; a_src = v<8?v:v-8,
  // b_src = v<4?v:v-4. Tile kt stages tile kt+1's constants.
  TILE(0, 1, 2, 3, 2, 3, true, "4", true);   // kt=0, stages tile1 (a2,3 b2,3)
  TILE(1, 0, 4, 5, 0, 1, true, "4", true);   // kt=1, stages tile2 (a4,5 b0,1)
  TILE(0, 1, 6, 7, 2, 3, true, "4", true);   // kt=2, stages tile3 (a6,7 b2,3)
  TILE(1, 0, 0, 1, 4, 5, true, "4", true);   // kt=3, stages tile4 (a0,1 b4,5)
  TILE(0, 1, 2, 3, 6, 7, true, "4", true);   // kt=4, stages tile5 (a2,3 b6,7)
  TILE(1, 0, 0, 0, 0, 0, false, "0", false); // kt=5, no staging; tail drain
#undef TILE
#undef PH0
#undef PH1
#undef PH2
#undef PH3

  // ---- Epilogue. C/D layout: col = lane&15, row = q*4 + reg. ----
  __syncthreads();  // all frag reads done before aliasing staging LDS
  const int jc0 = col0 + wn * 64 + lx;
  float bq[4];
  #pragma unroll
  for (int c = 0; c < 4; ++c) bq[c] = bsq[jc0 + 16 * c];

  #pragma unroll
  for (int m = 0; m < 8; ++m) {
    #pragma unroll
    for (int reg = 0; reg < 4; ++reg) {
      float bv = 1e30f; int bj = 0;
      #pragma unroll
      for (int c = 0; c < 4; ++c) {  // j ascending -> strict < keeps min j
        float val = fmaf(-2.f, acc[m][c][reg], bq[c]);
        if (val < bv) { bv = val; bj = jc0 + 16 * c; }
      }
      unsigned long long key = packkey(bv, bj);
      unsigned long long oth = __shfl_xor(key, 8, 64);  // fold col lx^8
      if (oth < key) key = oth;                         // u64 min keeps min j
      if ((lx & 8) == 0) {
        const int mrow = wm * 128 + m * 16 + 4 * q + reg;
        smem[mrow * 33 + wn * 8 + (lx & 7)] = key;      // pad-33
      }
    }
  }
  __syncthreads();
  if (t < 256) {
    unsigned long long best = ~0ull;
    #pragma unroll
    for (int c = 0; c < 32; ++c) {   // rotated read: spread banks across rows
      unsigned long long kx = smem[t * 33 + ((t + c) & 31)];
      if (kx < best) best = kx;
    }
    // Pre-filter: packed[] is monotone-decreasing; stale read only causes a
    // harmless extra atomic, never a lost minimum.
    unsigned long long cur = packed[row0 + t];
    if (best < cur) atomicMin(&packed[row0 + t], best);
  }
}

// ---------------------------------------------------------------------------
// Kernel 2: decode packed keys, write outputs.
// ---------------------------------------------------------------------------
__global__ __launch_bounds__(256) void out_kernel(
    const unsigned long long* __restrict__ packed,
    const float* __restrict__ asq, float* __restrict__ out) {
  int r = blockIdx.x * 256 + threadIdx.x;
  unsigned long long best = packed[r];
  unsigned u = (unsigned)(best >> 32);
  u = (u & 0x80000000u) ? (u & 0x7fffffffu) : ~u;   // invert monotone map
  float val  = __uint_as_float(u);
  float dist = sqrtf(fmaxf(asq[r] + val, 0.f));
  int j = (int)(unsigned)(best & 0xffffffffu);
  out[r]               = dist;
  out[NB1 + 2 * r]     = (float)r;
  out[NB1 + 2 * r + 1] = (float)j;
}

extern "C" void kernel_launch(void* const* d_in, const int* in_sizes, int n_in,
                              void* d_out, int out_size, void* d_ws, size_t ws_size,
                              hipStream_t stream) {
  const float* d1 = (const float*)d_in[0];
  const float* d2 = (const float*)d_in[1];
  float* out = (float*)d_out;

  char* w = (char*)d_ws;
  float* asq = (float*)w;                                   // 32 KB
  float* bsq = (float*)(w + 32768);                         // 32 KB
  _Float16* A2 = (_Float16*)(w + 65536);                    // 4 MB
  _Float16* B2 = (_Float16*)(w + 65536 + 4194304);          // 4 MB
  unsigned long long* packed =
      (unsigned long long*)(w + 65536 + 2 * 4194304);       // 64 KB

  convert_kernel<<<(NB1 + NB2) / 8, 256, 0, stream>>>(
      d1, d2, A2, B2, asq, bsq, packed);

  mfma_match_kernel<<<(NB1 / 256) * (NB2 / 256), 512, 0, stream>>>(
      A2, B2, bsq, packed);

  out_kernel<<<NB1 / 256, 256, 0, stream>>>(packed, asq, out);
}